// Round 11
// baseline (160.165 us; speedup 1.0000x reference)
//
#include <hip/hip_runtime.h>

// GRU fused, MI355X/gfx950 — round 11.
// r10 post-mortem: MB=64 amortization worked (88us, spill-free). But r2
// (2 desynced blocks/CU) had ~same per-row throughput with FAT math —
// the two wins never stacked. r11 = lean math x cross-block overlap:
//   MB=32, grid 512 -> 2 blocks/CU; 4 waves x (2 ut x 2 mt) per block;
//   LB(256,2) = 256-reg budget (r2-proven). While block A is in
//   gate-VALU/barrier, block B issues MFMA. 32-col waves halve per-CU
//   LDS h-read traffic (hb shared across ut).
// Keeps: folded sig/tanh scales, k28-bias row, cvt_pk packing, x register
// prefetch one step ahead, 1 barrier/step.

#define B_  16384
#define T_  28
#define F_  28
#define H_  128
#define C_  10
#define MB  32     // batch rows per block (2 tiles of 16)
#define LHS 136    // lh row stride in ushorts (272 B; balanced banks for b128/b64)

typedef short  short8  __attribute__((ext_vector_type(8)));
typedef float  f32x4   __attribute__((ext_vector_type(4)));
typedef unsigned uint4v __attribute__((ext_vector_type(4)));

__device__ __forceinline__ unsigned short f2bf(float f) {   // RNE fp32->bf16
    unsigned u = __builtin_bit_cast(unsigned, f);
    u += 0x7fffu + ((u >> 16) & 1u);
    return (unsigned short)(u >> 16);
}
__device__ __forceinline__ float bf2f(unsigned short h) {
    unsigned u = ((unsigned)h) << 16;
    return __builtin_bit_cast(float, u);
}
__device__ __forceinline__ unsigned cvt_pk_bf16(float lo, float hi) {
    unsigned r;
    asm("v_cvt_pk_bf16_f32 %0, %1, %2" : "=v"(r) : "v"(lo), "v"(hi));
    return r;
}

#define MS (-1.442695040888963f)   // z,r pre-scale (sig(x)=rcp(1+exp2(-x/ln2)))
#define TS ( 2.885390081777927f)   // tanh pre-scale (tanh=1-2*rcp(1+exp2(2x/ln2)))

__global__ __launch_bounds__(256, 2)
void gru_fused(const float* __restrict__ x,     // (B,T,F)
               const float* __restrict__ wk,    // (F,3H) = (28,384)
               const float* __restrict__ wrk,   // (H,3H) = (128,384)
               const float* __restrict__ bias,  // (2,3H)
               const float* __restrict__ dw,    // (H,C)
               const float* __restrict__ db,    // (C,)
               float* __restrict__ out)         // (B,C)
{
    // ---- LDS (~24 KB) -> 2 blocks/CU ----
    __shared__ __align__(16) unsigned short lh[2][MB*LHS];      // 17408 B, double-buffered
    __shared__ float ldw[H_*C_];                                // 5120 B
    __shared__ float llog[MB][C_];                              // 1280 B

    const int tid  = threadIdx.x;
    const int base = blockIdx.x * MB;
    const int lane = tid & 63;
    const int wc   = tid >> 6;    // wave id 0..3 -> 32-column slice (2 x 16)
    const int n    = lane & 15;   // B-operand outer (batch within tile) / D col
    const int q    = lane >> 4;   // MFMA quad

    // ---- loop-invariant weight fragments -> REGISTERS (120 VGPR/wave) ----
    // A-frag: elem(lane,j) = W'[k = kb*32 + q*8 + j][col], col = wc*32+ut*16+n
    // W' = W * MS (z,r) or W * TS (h). x-kernel k==28 row carries the bias.
    short8 wz[2][4], wr[2][4], wh[2][4];   // W_rec per [ut][kb]: 96 VGPR
    short8 xz[2], xr[2], xh[2];            // kernel (K pad 28->32, k28=bias): 24 VGPR
    #pragma unroll
    for (int ut = 0; ut < 2; ++ut) {
        const int col = wc*32 + ut*16 + n;
        #pragma unroll
        for (int kb = 0; kb < 4; ++kb) {
            const int k0 = kb*32 + q*8;
            short8 vz, vr, vh;
            #pragma unroll
            for (int j = 0; j < 8; ++j) {
                const float* wp = wrk + (size_t)(k0 + j)*384 + col;
                vz[j] = (short)f2bf(wp[0]   * MS);
                vr[j] = (short)f2bf(wp[128] * MS);
                vh[j] = (short)f2bf(wp[256] * TS);
            }
            wz[ut][kb] = vz; wr[ut][kb] = vr; wh[ut][kb] = vh;
        }
        short8 vz, vr, vh;
        #pragma unroll
        for (int j = 0; j < 8; ++j) {
            const int k = q*8 + j;
            if (k < F_) {
                const float* wp = wk + (size_t)k*384 + col;
                vz[j] = (short)f2bf(wp[0]   * MS);
                vr[j] = (short)f2bf(wp[128] * MS);
                vh[j] = (short)f2bf(wp[256] * TS);
            } else if (k == F_) {   // bias row (B-frag has 1.0 here)
                vz[j] = (short)f2bf((bias[col]       + bias[384 + col]) * MS);
                vr[j] = (short)f2bf((bias[128 + col] + bias[512 + col]) * MS);
                vh[j] = (short)f2bf( bias[256 + col]                    * TS);
            } else { vz[j] = 0; vr[j] = 0; vh[j] = 0; }
        }
        xz[ut] = vz; xr[ut] = vr; xh[ut] = vh;
    }

    // br_h (rec-h acc init), pre-scaled: 8 VGPR
    f32x4 bh4[2];
    #pragma unroll
    for (int ut = 0; ut < 2; ++ut)
        #pragma unroll
        for (int reg = 0; reg < 4; ++reg)
            bh4[ut][reg] = bias[640 + wc*32 + ut*16 + q*4 + reg] * TS;

    // ---- dense weights / h0 ----
    for (int i = tid; i < H_*C_; i += 256) ldw[i] = dw[i];
    for (int i = tid; i < MB*LHS/2; i += 256) ((unsigned*)lh[0])[i] = 0u;

    __syncthreads();   // init visible

    float hm[2][2][4];            // fp32 h master [ut][mt][reg]
    #pragma unroll
    for (int ut = 0; ut < 2; ++ut)
        #pragma unroll
        for (int mt = 0; mt < 2; ++mt)
            #pragma unroll
            for (int r = 0; r < 4; ++r) hm[ut][mt][r] = 0.f;

    // per-mt x row pointers + prefetch t=0 (16 VGPR)
    const int xo1 = q*8;
    const int xo2 = (q < 3) ? q*8 + 4 : 24;   // clamped: in-bounds garbage x zero-weight
    const bool q3 = (q == 3);
    const float* xrw[2];
    float4 xa0[2], xa1[2];
    #pragma unroll
    for (int mt = 0; mt < 2; ++mt) {
        xrw[mt] = x + (size_t)(base + mt*16 + n)*(T_*F_);
        xa0[mt] = *(const float4*)(xrw[mt] + xo1);
        xa1[mt] = *(const float4*)(xrw[mt] + xo2);
    }

    const int wbase = wc*32 + q*4;    // unit base this lane owns (ut adds 16)

    #pragma unroll 1
    for (int t = 0; t < T_; ++t) {
        const unsigned short* __restrict__ lhr = lh[t & 1];
        unsigned short* __restrict__ lhw = lh[(t + 1) & 1];
        const bool pn = (t + 1 < T_);

        // x B-frags + next-step prefetch + h B-frags (shared across ut)
        short8 xbv[2]; short8 hb[2][4];
        #pragma unroll
        for (int mt = 0; mt < 2; ++mt) {
            uint4v xv;
            xv[0] = cvt_pk_bf16(xa0[mt].x, xa0[mt].y);
            xv[1] = cvt_pk_bf16(xa0[mt].z, xa0[mt].w);
            xv[2] = q3 ? 0x3f80u : cvt_pk_bf16(xa1[mt].x, xa1[mt].y);
            xv[3] = cvt_pk_bf16(xa1[mt].z, xa1[mt].w);
            xbv[mt] = __builtin_bit_cast(short8, xv);
            if (pn) {
                xa0[mt] = *(const float4*)(xrw[mt] + (t+1)*F_ + xo1);
                xa1[mt] = *(const float4*)(xrw[mt] + (t+1)*F_ + xo2);
            }
            const int rbase = (mt*16 + n)*LHS;
            #pragma unroll
            for (int kb = 0; kb < 4; ++kb)
                hb[mt][kb] = *(const short8*)&lhr[rbase + kb*32 + q*8];
        }

        // per ut-slice: 2 independent mt MFMA chains, then gates
        #pragma unroll
        for (int ut = 0; ut < 2; ++ut) {
            f32x4 az[2], ag[2], ax[2], ah[2];
            #pragma unroll
            for (int mt = 0; mt < 2; ++mt) {
                az[mt] = (f32x4){0.f,0.f,0.f,0.f};
                ag[mt] = (f32x4){0.f,0.f,0.f,0.f};
                ax[mt] = (f32x4){0.f,0.f,0.f,0.f};
                ah[mt] = bh4[ut];
                #pragma unroll
                for (int kb = 0; kb < 4; ++kb) {
                    az[mt] = __builtin_amdgcn_mfma_f32_16x16x32_bf16(wz[ut][kb], hb[mt][kb], az[mt], 0,0,0);
                    ag[mt] = __builtin_amdgcn_mfma_f32_16x16x32_bf16(wr[ut][kb], hb[mt][kb], ag[mt], 0,0,0);
                    ah[mt] = __builtin_amdgcn_mfma_f32_16x16x32_bf16(wh[ut][kb], hb[mt][kb], ah[mt], 0,0,0);
                }
                az[mt] = __builtin_amdgcn_mfma_f32_16x16x32_bf16(xz[ut], xbv[mt], az[mt], 0,0,0);
                ag[mt] = __builtin_amdgcn_mfma_f32_16x16x32_bf16(xr[ut], xbv[mt], ag[mt], 0,0,0);
                ax[mt] = __builtin_amdgcn_mfma_f32_16x16x32_bf16(xh[ut], xbv[mt], ax[mt], 0,0,0);
            }
            // gates (pre-scaled accs): z=rcp(1+exp2(az)), hh=1-2*rcp(1+exp2(ax+r*ah))
            #pragma unroll
            for (int mt = 0; mt < 2; ++mt) {
                float hn[4];
                #pragma unroll
                for (int reg = 0; reg < 4; ++reg) {
                    float z  = __builtin_amdgcn_rcpf(1.0f + __builtin_amdgcn_exp2f(az[mt][reg]));
                    float r  = __builtin_amdgcn_rcpf(1.0f + __builtin_amdgcn_exp2f(ag[mt][reg]));
                    float ta = ax[mt][reg] + r * ah[mt][reg];
                    float hh = 1.0f - 2.0f * __builtin_amdgcn_rcpf(1.0f + __builtin_amdgcn_exp2f(ta));
                    float hv = hh + z * (hm[ut][mt][reg] - hh);
                    hm[ut][mt][reg] = hv; hn[reg] = hv;
                }
                uint2 pk;
                pk.x = cvt_pk_bf16(hn[0], hn[1]);
                pk.y = cvt_pk_bf16(hn[2], hn[3]);
                *(uint2*)&lhw[(mt*16 + n)*LHS + wbase + ut*16] = pk;
            }
        }

        __syncthreads();   // h_{t+1} published
    }

    // ---- dense + softmax epilogue (final h in lh[0]: last write t=27 -> (27+1)&1) ----
    for (int i = tid; i < MB*C_; i += 256) {
        const int row = i / C_, c = i - row*C_;
        float s = db[c];
        #pragma unroll
        for (int u0 = 0; u0 < H_; u0 += 8) {
            short8 hv = *(const short8*)&lh[0][row*LHS + u0];
            #pragma unroll
            for (int j = 0; j < 8; ++j)
                s += bf2f((unsigned short)hv[j]) * ldw[(u0+j)*C_ + c];
        }
        llog[row][c] = s;
    }
    __syncthreads();
    if (tid < MB) {
        const int row = tid;
        float m = llog[row][0];
        #pragma unroll
        for (int c = 1; c < C_; ++c) m = fmaxf(m, llog[row][c]);
        float e[C_], s = 0.f;
        #pragma unroll
        for (int c = 0; c < C_; ++c) {
            e[c] = __builtin_amdgcn_exp2f((llog[row][c] - m) * 1.442695040888963f);
            s += e[c];
        }
        const float inv = __builtin_amdgcn_rcpf(s);
        float* o = out + (size_t)(base + row)*C_;
        #pragma unroll
        for (int c = 0; c < C_; ++c) o[c] = e[c] * inv;
    }
}

extern "C" void kernel_launch(void* const* d_in, const int* in_sizes, int n_in,
                              void* d_out, int out_size, void* d_ws, size_t ws_size,
                              hipStream_t stream) {
    const float* x   = (const float*)d_in[0];
    const float* wk  = (const float*)d_in[1];
    const float* wrk = (const float*)d_in[2];
    const float* bs  = (const float*)d_in[3];
    const float* dw  = (const float*)d_in[4];
    const float* db  = (const float*)d_in[5];
    (void)in_sizes; (void)n_in; (void)out_size; (void)d_ws; (void)ws_size;
    gru_fused<<<dim3(B_/MB), dim3(256), 0, stream>>>(x, wk, wrk, bs, dw, db, (float*)d_out);
}